// Round 10
// baseline (74.277 us; speedup 1.0000x reference)
//
#include <hip/hip_runtime.h>
#include <math.h>

#define B_    4
#define TDEC  512
#define TENC  1024
#define H_    128
#define DT    4

// exp(2*enc) transposed+packed: [b][g:32][e:1024][j:4]  (lane-contiguous in e)
__device__ float g_ebp[(size_t)B_ * 32 * TENC * 4];   // 2 MB
// per (row-tile rt, g): [V4(4), Ea_d0(4), Ea_d1(4), Ea_d2(4), Ea_d3(4)] = 20 f
__device__ float g_eav[(size_t)B_ * 128 * 32 * 20];   // 1.3 MB
__device__ float g_sv[1];                             // sum(V_w)

struct EAV { float4 v4, ea0, ea1, ea2, ea3; };
union F4 { float4 v; float f[4]; };

// z<4: transpose enc, store exp(2*enc) -> g_ebp.   z==4: Ea rows + V pack + SV.
__global__ __launch_bounds__(256) void prep_kernel(const float* __restrict__ enc,
                                                   const float* __restrict__ dec,
                                                   const float* __restrict__ Ww,
                                                   const float* __restrict__ Wb,
                                                   const float* __restrict__ Vw) {
    const int z = blockIdx.z;
    const int tx = threadIdx.x, ty = threadIdx.y;
    if (z < B_) {
        __shared__ float tile[32][33];               // [e-local][h-local]
        const int e0 = blockIdx.x * 32, h0 = blockIdx.y * 32, b = z;
        const float* ep = enc + (size_t)b * TENC * H_;
        #pragma unroll
        for (int j = 0; j < 32; j += 8)
            tile[ty + j][tx] = ep[(size_t)(e0 + ty + j) * H_ + h0 + tx];
        __syncthreads();
        // thread (tx,ty): e = e0+tx, g = h0/4+ty -> one float4 store of exp(2x)
        const int g = (h0 >> 2) + ty, e = e0 + tx;
        float4 o;
        o.x = __expf(2.f * tile[tx][4 * ty + 0]);
        o.y = __expf(2.f * tile[tx][4 * ty + 1]);
        o.z = __expf(2.f * tile[tx][4 * ty + 2]);
        o.w = __expf(2.f * tile[tx][4 * ty + 3]);
        *(float4*)&g_ebp[(((size_t)b * 32 + g) * TENC + e) * 4] = o;
    } else {
        // 128 blocks x 16 rows: Ea = exp(2*(dec @ Ww^T + Wb)); pack Ea & V
        __shared__ float ds[16][H_];
        const int t = ty * 32 + tx;
        const int blk = blockIdx.y * 32 + blockIdx.x;      // 0..127
        const int R0 = blk * 16;
        #pragma unroll
        for (int i = 0; i < 8; ++i) {
            const int f = t + 256 * i;
            ds[f >> 7][f & 127] = dec[(size_t)R0 * H_ + f];
        }
        __syncthreads();
        const int k = t & 127, dd = t >> 7;
        const float* wr = Ww + (size_t)k * H_;
        float s[8];
        #pragma unroll
        for (int j = 0; j < 8; ++j) s[j] = 0.f;
        for (int h = 0; h < H_; h += 4) {
            const float4 w4 = *(const float4*)(wr + h);
            #pragma unroll
            for (int j = 0; j < 8; ++j) {
                const float4 d4 = *(const float4*)&ds[dd + 2 * j][h];
                s[j] = fmaf(w4.x, d4.x, s[j]);
                s[j] = fmaf(w4.y, d4.y, s[j]);
                s[j] = fmaf(w4.z, d4.z, s[j]);
                s[j] = fmaf(w4.w, d4.w, s[j]);
            }
        }
        const float wb = Wb[k], vw = Vw[k];
        const int g = k >> 2, jj = k & 3;
        #pragma unroll
        for (int j = 0; j < 8; ++j) {
            const int rl = dd + 2 * j;          // row within 16-row block
            const int R = R0 + rl;
            const float ea = __expf(2.f * (s[j] + wb));
            g_eav[((size_t)(R >> 2) * 32 + g) * 20 + 4 + (R & 3) * 4 + jj] = ea;
        }
        if (dd == 0) {
            #pragma unroll
            for (int r = 0; r < 4; ++r)
                g_eav[((size_t)((R0 >> 2) + r) * 32 + g) * 20 + jj] = vw;
        }
        if (blk == 0) {
            __shared__ float svp[2];
            if (t < 128) {
                float x = vw;
                #pragma unroll
                for (int off = 32; off; off >>= 1) x += __shfl_xor(x, off);
                if ((t & 63) == 0) svp[t >> 6] = x;
            }
            __syncthreads();
            if (t == 0) g_sv[0] = svp[0] + svp[1];
        }
    }
}

// 4-h fraction combine: sum_i V_i/p_i with p_i = 1 + Ea_i*Eb_i; one rcp.
__device__ __forceinline__ float term4(const float4 ea, const float4 v4,
                                       const F4 te, float acc) {
    const float p0 = fmaf(ea.x, te.f[0], 1.f);
    const float p1 = fmaf(ea.y, te.f[1], 1.f);
    const float p2 = fmaf(ea.z, te.f[2], 1.f);
    const float p3 = fmaf(ea.w, te.f[3], 1.f);
    const float p01 = p0 * p1, p23 = p2 * p3;
    const float a  = fmaf(v4.y, p0, v4.x * p1);
    const float bq = fmaf(v4.w, p2, v4.z * p3);
    const float num = fmaf(bq, p01, a * p23);
    return fmaf(num, __builtin_amdgcn_rcpf(p01 * p23), acc);
}

#define DALL(S, TE)                         \
    acc0 = term4(S.ea0, S.v4, TE, acc0);    \
    acc1 = term4(S.ea1, S.v4, TE, acc1);    \
    acc2 = term4(S.ea2, S.v4, TE, acc2);    \
    acc3 = term4(S.ea3, S.v4, TE, acc3);

// Keep prefetched registers alive at this point (stop the allocator from
// sinking the load to the use site and collapsing the software pipeline).
#define PIN(X) asm volatile("" : "+v"((X).f[0]), "+v"((X).f[1]), \
                                 "+v"((X).f[2]), "+v"((X).f[3]))

// Fused: score + softmax(sum-only) + context + write.  Block = 1 row-tile
// (4 rows), 1024 threads (thread owns 1 e); grid 512 -> 2 blocks/CU.
// te prefetched 2 iterations deep, asm-pinned.
__global__ __launch_bounds__(1024, 8) void fused_kernel(const float* __restrict__ enc,
                                                        float* __restrict__ out) {
    __shared__ float sc[DT][TENC];          // p = exp(score)      (16 KB)
    __shared__ float2 part[16][DT][64];     // context partials    (32 KB)
    __shared__ float wsum[16][DT];
    __shared__ float rsum[DT];

    const int t = threadIdx.x;
    // XCD-locality swizzle: 512 blocks, 8 XCDs; give XCD x one contiguous
    // 64-row-tile chunk (single b per XCD -> enc+te working set ~2.7MB < 4MB L2).
    const int bid = blockIdx.x;
    const int rt = (bid & 7) * 64 + (bid >> 3);
    const int b = rt >> 7;
    const int R0 = rt * DT;
    const EAV* epk = (const EAV*)g_eav + (size_t)rt * 32;
    const float* teb = g_ebp + (size_t)b * 32 * (TENC * 4) + t * 4;
    const float sv = g_sv[0];

    // --- Phase 1: scores (barrier-free; EAV via uniform s_loads) ---
    float acc0 = 0.f, acc1 = 0.f, acc2 = 0.f, acc3 = 0.f;

    F4 tea, teb4;
    tea.v  = *(const float4*)teb;
    teb4.v = *(const float4*)(teb + 1 * (TENC * 4));
    PIN(tea); PIN(teb4);
    EAV A  = epk[0];
    EAV Bv = epk[1];

    for (int g = 0; g < 32; g += 2) {
        const int g2 = (g + 2) & 31, g3 = (g + 3) & 31;   // wrap: tail dummies
        F4 tec, ted;
        tec.v = *(const float4*)(teb + (size_t)g2 * (TENC * 4));
        PIN(tec);
        EAV C = epk[g2];

        DALL(A, tea);

        ted.v = *(const float4*)(teb + (size_t)g3 * (TENC * 4));
        PIN(ted);
        EAV D = epk[g3];

        DALL(Bv, teb4);

        tea = tec; teb4 = ted; A = C; Bv = D;
    }

    // --- Phase 2: p = exp(score); stash + per-wave partial sums ---
    const float q0 = __expf(fmaf(-2.f, acc0, sv));
    const float q1 = __expf(fmaf(-2.f, acc1, sv));
    const float q2 = __expf(fmaf(-2.f, acc2, sv));
    const float q3 = __expf(fmaf(-2.f, acc3, sv));
    sc[0][t] = q0; sc[1][t] = q1; sc[2][t] = q2; sc[3][t] = q3;

    float s0 = q0, s1 = q1, s2 = q2, s3 = q3;
    #pragma unroll
    for (int off = 32; off; off >>= 1) {
        s0 += __shfl_xor(s0, off);
        s1 += __shfl_xor(s1, off);
        s2 += __shfl_xor(s2, off);
        s3 += __shfl_xor(s3, off);
    }
    {
        const int w = t >> 6, lane = t & 63;
        if (lane == 0) { wsum[w][0] = s0; wsum[w][1] = s1; wsum[w][2] = s2; wsum[w][3] = s3; }
    }
    __syncthreads();
    if (t < 64) {                            // lane = w'*4 + d
        float x = wsum[t >> 2][t & 3];
        #pragma unroll
        for (int off = 4; off < 64; off <<= 1) x += __shfl_xor(x, off);
        if (t < 4) rsum[t] = x;
    }

    // --- Phase 3: context partials; thread = (q = e-slice of 64, h2) ---
    {
        const int q = t >> 6, h2 = t & 63;
        const float* eb = enc + (size_t)b * TENC * H_ + 2 * h2;
        float2 a0 = {0.f, 0.f}, a1 = {0.f, 0.f}, a2 = {0.f, 0.f}, a3 = {0.f, 0.f};
        const int e0 = q * 64;
        for (int e = e0; e < e0 + 64; e += 4) {
            F4 u0, u1, u2, u3;
            u0.v = *(const float4*)&sc[0][e];
            u1.v = *(const float4*)&sc[1][e];
            u2.v = *(const float4*)&sc[2][e];
            u3.v = *(const float4*)&sc[3][e];
            #pragma unroll
            for (int j = 0; j < 4; ++j) {
                const float2 ev = *(const float2*)(eb + (size_t)(e + j) * H_);
                a0.x = fmaf(u0.f[j], ev.x, a0.x); a0.y = fmaf(u0.f[j], ev.y, a0.y);
                a1.x = fmaf(u1.f[j], ev.x, a1.x); a1.y = fmaf(u1.f[j], ev.y, a1.y);
                a2.x = fmaf(u2.f[j], ev.x, a2.x); a2.y = fmaf(u2.f[j], ev.y, a2.y);
                a3.x = fmaf(u3.f[j], ev.x, a3.x); a3.y = fmaf(u3.f[j], ev.y, a3.y);
            }
        }
        part[q][0][h2] = a0; part[q][1][h2] = a1;
        part[q][2][h2] = a2; part[q][3][h2] = a3;
    }
    __syncthreads();

    // --- Phase 4: merge 16 slices, divide, write ---
    if (t < 256) {
        const int d = t >> 6, h2 = t & 63;
        float2 s = {0.f, 0.f};
        #pragma unroll
        for (int q = 0; q < 16; ++q) {
            const float2 pp = part[q][d][h2];
            s.x += pp.x; s.y += pp.y;
        }
        const float rinv = __builtin_amdgcn_rcpf(rsum[d]);
        s.x *= rinv; s.y *= rinv;
        *(float2*)(out + (size_t)(R0 + d) * H_ + 2 * h2) = s;
    }
}

extern "C" void kernel_launch(void* const* d_in, const int* in_sizes, int n_in,
                              void* d_out, int out_size, void* d_ws, size_t ws_size,
                              hipStream_t stream) {
    const float* dec = (const float*)d_in[0];
    const float* enc = (const float*)d_in[1];
    const float* Ww  = (const float*)d_in[2];
    const float* Wb  = (const float*)d_in[3];
    const float* Vw  = (const float*)d_in[4];
    float* out = (float*)d_out;

    prep_kernel<<<dim3(TENC / 32, H_ / 32, B_ + 1), dim3(32, 8), 0, stream>>>(
        enc, dec, Ww, Wb, Vw);
    fused_kernel<<<dim3(B_ * 128), dim3(1024), 0, stream>>>(enc, out);
}

// Round 11
// 58.726 us; speedup vs baseline: 1.2648x; 1.2648x over previous
//
#include <hip/hip_runtime.h>
#include <math.h>

#define B_    4
#define TDEC  512
#define TENC  1024
#define H_    128
#define DT    4

// exp(2*enc) transposed+packed: [b][g:32][e:1024][j:4]  (lane-contiguous in e)
__device__ float g_ebp[(size_t)B_ * 32 * TENC * 4];   // 2 MB
// per (row-tile rt, g): [V4(4), Ea_d0(4), Ea_d1(4), Ea_d2(4), Ea_d3(4)] = 20 f
__device__ float g_eav[(size_t)B_ * 128 * 32 * 20];   // 1.3 MB
__device__ float g_sv[1];                             // sum(V_w)

struct EAV { float4 v4, ea0, ea1, ea2, ea3; };
union F4 { float4 v; float f[4]; };

// z<4: transpose enc, store exp(2*enc) -> g_ebp.   z==4: Ea rows + V pack + SV.
__global__ __launch_bounds__(256) void prep_kernel(const float* __restrict__ enc,
                                                   const float* __restrict__ dec,
                                                   const float* __restrict__ Ww,
                                                   const float* __restrict__ Wb,
                                                   const float* __restrict__ Vw) {
    const int z = blockIdx.z;
    const int tx = threadIdx.x, ty = threadIdx.y;
    if (z < B_) {
        __shared__ float tile[32][33];               // [e-local][h-local]
        const int e0 = blockIdx.x * 32, h0 = blockIdx.y * 32, b = z;
        const float* ep = enc + (size_t)b * TENC * H_;
        #pragma unroll
        for (int j = 0; j < 32; j += 8)
            tile[ty + j][tx] = ep[(size_t)(e0 + ty + j) * H_ + h0 + tx];
        __syncthreads();
        // thread (tx,ty): e = e0+tx, g = h0/4+ty -> one float4 store of exp(2x)
        const int g = (h0 >> 2) + ty, e = e0 + tx;
        float4 o;
        o.x = __expf(2.f * tile[tx][4 * ty + 0]);
        o.y = __expf(2.f * tile[tx][4 * ty + 1]);
        o.z = __expf(2.f * tile[tx][4 * ty + 2]);
        o.w = __expf(2.f * tile[tx][4 * ty + 3]);
        *(float4*)&g_ebp[(((size_t)b * 32 + g) * TENC + e) * 4] = o;
    } else {
        // 128 blocks x 16 rows: Ea = exp(2*(dec @ Ww^T + Wb)); pack Ea & V
        __shared__ float ds[16][H_];
        const int t = ty * 32 + tx;
        const int blk = blockIdx.y * 32 + blockIdx.x;      // 0..127
        const int R0 = blk * 16;
        #pragma unroll
        for (int i = 0; i < 8; ++i) {
            const int f = t + 256 * i;
            ds[f >> 7][f & 127] = dec[(size_t)R0 * H_ + f];
        }
        __syncthreads();
        const int k = t & 127, dd = t >> 7;
        const float* wr = Ww + (size_t)k * H_;
        float s[8];
        #pragma unroll
        for (int j = 0; j < 8; ++j) s[j] = 0.f;
        for (int h = 0; h < H_; h += 4) {
            const float4 w4 = *(const float4*)(wr + h);
            #pragma unroll
            for (int j = 0; j < 8; ++j) {
                const float4 d4 = *(const float4*)&ds[dd + 2 * j][h];
                s[j] = fmaf(w4.x, d4.x, s[j]);
                s[j] = fmaf(w4.y, d4.y, s[j]);
                s[j] = fmaf(w4.z, d4.z, s[j]);
                s[j] = fmaf(w4.w, d4.w, s[j]);
            }
        }
        const float wb = Wb[k], vw = Vw[k];
        const int g = k >> 2, jj = k & 3;
        #pragma unroll
        for (int j = 0; j < 8; ++j) {
            const int rl = dd + 2 * j;          // row within 16-row block
            const int R = R0 + rl;
            const float ea = __expf(2.f * (s[j] + wb));
            g_eav[((size_t)(R >> 2) * 32 + g) * 20 + 4 + (R & 3) * 4 + jj] = ea;
        }
        if (dd == 0) {
            #pragma unroll
            for (int r = 0; r < 4; ++r)
                g_eav[((size_t)((R0 >> 2) + r) * 32 + g) * 20 + jj] = vw;
        }
        if (blk == 0) {
            __shared__ float svp[2];
            if (t < 128) {
                float x = vw;
                #pragma unroll
                for (int off = 32; off; off >>= 1) x += __shfl_xor(x, off);
                if ((t & 63) == 0) svp[t >> 6] = x;
            }
            __syncthreads();
            if (t == 0) g_sv[0] = svp[0] + svp[1];
        }
    }
}

// 4-h fraction combine: sum_i V_i/p_i with p_i = 1 + Ea_i*Eb_i; one rcp.
__device__ __forceinline__ float term4(const float4 ea, const float4 v4,
                                       const F4 te, float acc) {
    const float p0 = fmaf(ea.x, te.f[0], 1.f);
    const float p1 = fmaf(ea.y, te.f[1], 1.f);
    const float p2 = fmaf(ea.z, te.f[2], 1.f);
    const float p3 = fmaf(ea.w, te.f[3], 1.f);
    const float p01 = p0 * p1, p23 = p2 * p3;
    const float a  = fmaf(v4.y, p0, v4.x * p1);
    const float bq = fmaf(v4.w, p2, v4.z * p3);
    const float num = fmaf(bq, p01, a * p23);
    return fmaf(num, __builtin_amdgcn_rcpf(p01 * p23), acc);
}

// Process both e-streams of one g with one EAV pack (8 term4, 2 loads' worth)
#define DALL2(S, TEa, TEb)                   \
    acc0 = term4(S.ea0, S.v4, TEa, acc0);    \
    acc1 = term4(S.ea1, S.v4, TEa, acc1);    \
    acc2 = term4(S.ea2, S.v4, TEa, acc2);    \
    acc3 = term4(S.ea3, S.v4, TEa, acc3);    \
    bcc0 = term4(S.ea0, S.v4, TEb, bcc0);    \
    bcc1 = term4(S.ea1, S.v4, TEb, bcc1);    \
    bcc2 = term4(S.ea2, S.v4, TEb, bcc2);    \
    bcc3 = term4(S.ea3, S.v4, TEb, bcc3);

// Fused: score + softmax(sum-only) + context + write.  Block = 1 row-tile
// (4 rows), 512 threads; thread owns e=t and e=t+512 (2 independent load
// streams -> MLP=2).  Grid 512, 4 blocks/CU, 8 waves/SIMD (100% cap).
__global__ __launch_bounds__(512, 8) void fused_kernel(const float* __restrict__ enc,
                                                       float* __restrict__ out) {
    __shared__ float sc[DT][TENC];          // p = exp(score)      (16 KB)
    __shared__ float2 part[8][DT][64];      // context partials    (16 KB)
    __shared__ float wsum[8][DT];
    __shared__ float rsum[DT];

    const int t = threadIdx.x;
    // XCD-locality swizzle: block bid runs on XCD bid%8; give each XCD a
    // contiguous 64-row-tile chunk (all same b -> ~1.3MB working set < 4MB L2).
    const int bid = blockIdx.x;
    const int rt = (bid & 7) * 64 + (bid >> 3);
    const int b = rt >> 7;
    const int R0 = rt * DT;
    const EAV* epk = (const EAV*)g_eav + (size_t)rt * 32;
    const float* te0 = g_ebp + (size_t)b * 32 * (TENC * 4) + t * 4;         // e=t
    const float* te1 = te0 + 512 * 4;                                       // e=t+512
    const float sv = g_sv[0];

    // --- Phase 1: scores; 2-deep prefetch, two e-streams per thread ---
    float acc0 = 0.f, acc1 = 0.f, acc2 = 0.f, acc3 = 0.f;
    float bcc0 = 0.f, bcc1 = 0.f, bcc2 = 0.f, bcc3 = 0.f;

    EAV A  = epk[0];
    EAV Bv = epk[1];
    F4 a0, a1, b0, b1;
    a0.v = *(const float4*)te0;
    a1.v = *(const float4*)te1;
    b0.v = *(const float4*)(te0 + TENC * 4);
    b1.v = *(const float4*)(te1 + TENC * 4);

    for (int g = 0; g < 32; g += 2) {
        const int g2 = (g + 2) & 31, g3 = (g + 3) & 31;   // wrap: tail dummies
        F4 c0, c1, d0, d1;
        c0.v = *(const float4*)(te0 + (size_t)g2 * (TENC * 4));
        c1.v = *(const float4*)(te1 + (size_t)g2 * (TENC * 4));
        EAV C = epk[g2];

        DALL2(A, a0, a1);

        d0.v = *(const float4*)(te0 + (size_t)g3 * (TENC * 4));
        d1.v = *(const float4*)(te1 + (size_t)g3 * (TENC * 4));
        EAV D = epk[g3];

        DALL2(Bv, b0, b1);

        a0 = c0; a1 = c1; b0 = d0; b1 = d1; A = C; Bv = D;
    }

    // --- Phase 2: p = exp(score); stash + per-wave partial sums ---
    const float q0 = __expf(fmaf(-2.f, acc0, sv));
    const float q1 = __expf(fmaf(-2.f, acc1, sv));
    const float q2 = __expf(fmaf(-2.f, acc2, sv));
    const float q3 = __expf(fmaf(-2.f, acc3, sv));
    const float r0 = __expf(fmaf(-2.f, bcc0, sv));
    const float r1 = __expf(fmaf(-2.f, bcc1, sv));
    const float r2 = __expf(fmaf(-2.f, bcc2, sv));
    const float r3 = __expf(fmaf(-2.f, bcc3, sv));
    sc[0][t] = q0; sc[1][t] = q1; sc[2][t] = q2; sc[3][t] = q3;
    sc[0][t + 512] = r0; sc[1][t + 512] = r1; sc[2][t + 512] = r2; sc[3][t + 512] = r3;

    float s0 = q0 + r0, s1 = q1 + r1, s2 = q2 + r2, s3 = q3 + r3;
    #pragma unroll
    for (int off = 32; off; off >>= 1) {
        s0 += __shfl_xor(s0, off);
        s1 += __shfl_xor(s1, off);
        s2 += __shfl_xor(s2, off);
        s3 += __shfl_xor(s3, off);
    }
    {
        const int w = t >> 6, lane = t & 63;
        if (lane == 0) { wsum[w][0] = s0; wsum[w][1] = s1; wsum[w][2] = s2; wsum[w][3] = s3; }
    }
    __syncthreads();
    if (t < 32) {                            // lane = w'*4 + d, w' = 0..7
        float x = wsum[t >> 2][t & 3];
        #pragma unroll
        for (int off = 4; off < 32; off <<= 1) x += __shfl_xor(x, off);
        if (t < 4) rsum[t] = x;
    }

    // --- Phase 3: context partials; thread = (q = e-slice of 128, h2) ---
    {
        const int q = t >> 6, h2 = t & 63;
        const float* eb = enc + (size_t)b * TENC * H_ + 2 * h2;
        float2 a0c = {0.f, 0.f}, a1c = {0.f, 0.f}, a2c = {0.f, 0.f}, a3c = {0.f, 0.f};
        const int e0 = q * 128;
        for (int e = e0; e < e0 + 128; e += 4) {
            F4 u0, u1, u2, u3;
            u0.v = *(const float4*)&sc[0][e];
            u1.v = *(const float4*)&sc[1][e];
            u2.v = *(const float4*)&sc[2][e];
            u3.v = *(const float4*)&sc[3][e];
            #pragma unroll
            for (int j = 0; j < 4; ++j) {
                const float2 ev = *(const float2*)(eb + (size_t)(e + j) * H_);
                a0c.x = fmaf(u0.f[j], ev.x, a0c.x); a0c.y = fmaf(u0.f[j], ev.y, a0c.y);
                a1c.x = fmaf(u1.f[j], ev.x, a1c.x); a1c.y = fmaf(u1.f[j], ev.y, a1c.y);
                a2c.x = fmaf(u2.f[j], ev.x, a2c.x); a2c.y = fmaf(u2.f[j], ev.y, a2c.y);
                a3c.x = fmaf(u3.f[j], ev.x, a3c.x); a3c.y = fmaf(u3.f[j], ev.y, a3c.y);
            }
        }
        part[q][0][h2] = a0c; part[q][1][h2] = a1c;
        part[q][2][h2] = a2c; part[q][3][h2] = a3c;
    }
    __syncthreads();

    // --- Phase 4: merge 8 slices, divide, write ---
    if (t < 256) {
        const int d = t >> 6, h2 = t & 63;
        float2 s = {0.f, 0.f};
        #pragma unroll
        for (int q = 0; q < 8; ++q) {
            const float2 pp = part[q][d][h2];
            s.x += pp.x; s.y += pp.y;
        }
        const float rinv = __builtin_amdgcn_rcpf(rsum[d]);
        s.x *= rinv; s.y *= rinv;
        *(float2*)(out + (size_t)(R0 + d) * H_ + 2 * h2) = s;
    }
}

extern "C" void kernel_launch(void* const* d_in, const int* in_sizes, int n_in,
                              void* d_out, int out_size, void* d_ws, size_t ws_size,
                              hipStream_t stream) {
    const float* dec = (const float*)d_in[0];
    const float* enc = (const float*)d_in[1];
    const float* Ww  = (const float*)d_in[2];
    const float* Wb  = (const float*)d_in[3];
    const float* Vw  = (const float*)d_in[4];
    float* out = (float*)d_out;

    prep_kernel<<<dim3(TENC / 32, H_ / 32, B_ + 1), dim3(32, 8), 0, stream>>>(
        enc, dec, Ww, Wb, Vw);
    fused_kernel<<<dim3(B_ * 128), dim3(512), 0, stream>>>(enc, out);
}